// Round 20
// baseline (257.072 us; speedup 1.0000x reference)
//
#include <hip/hip_runtime.h>
#include <hip/hip_fp16.h>
#include <hip/hip_cooperative_groups.h>
#include <math.h>

namespace cg = cooperative_groups;

#define N_CELLS 65536
#define HIDDEN  128
#define IN_DIM  64
#define MAX_DEG 6
#define NXCD    8

// fused config
#define NBLKF    512                // cooperative grid: needs only 2 blocks/CU
#define NODES_PB 128                // nodes per block
#define WPB      4                  // waves per block
#define CITER    16                 // wave iterations (2 nodes/iter)

// fallback config (R16)
#define NPB_B    32
#define NBLK_B   (N_CELLS/NPB_B)    // 2048
#define CHUNK_B  4

#define INV2PI 0.15915494309189535f

__device__ __forceinline__ void fsincos(float x, float& s, float& c) {
    const float r = x * INV2PI;                     // revolutions for v_sin/v_cos
    s = __builtin_amdgcn_sinf(r);
    c = __builtin_amdgcn_cosf(r);
}

// ---------------- ws offsets (~40.5 MB, shared by both paths) ----------------
#define WS_PP    0                                   // 128 f32
#define WS_FLAG  512                                 // 1 int
#define WS_STR   1024                                // 65536 f32
#define WS_T     (1024 + N_CELLS*4)                  // 32 MB: 4x half2{theta,amp}/lane
#define WS_ADJ   (WS_T + (size_t)N_CELLS*512)        // 2 MB (fallback only)
#define WS_P     (WS_ADJ + (size_t)N_CELLS*32)       // 256 x 2048 f32 (2 MB, both strides fit)
#define WS_SA    (WS_P + 256*NBLK_B*4)               // 2048 f32
#define WS_SA2   (WS_SA + NBLK_B*4)                  // 2048 f32
#define WS_MEAN  (WS_SA2 + NBLK_B*4)                 // 256 f32

// ========================== FUSED cooperative kernel =========================
__global__ __launch_bounds__(256, 2) void k_fused(
    const float* __restrict__ amp, const float* __restrict__ phase,
    const float* __restrict__ vel,
    const float* __restrict__ x, const float* __restrict__ W_in,
    const float* __restrict__ b_in, const unsigned char* __restrict__ maskb,
    const int* __restrict__ nbr_idx, const float* __restrict__ nbr_sign,
    const int* __restrict__ step,
    int4* __restrict__ T, float* __restrict__ strength,
    float* __restrict__ pp, int* __restrict__ flag,
    float* __restrict__ P, float* __restrict__ p_sa, float* __restrict__ p_sa2,
    float* __restrict__ meanb,
    const float* __restrict__ W_dec, const float* __restrict__ b_dec,
    float* __restrict__ out)
{
    cg::grid_group grid = cg::this_grid();

    __shared__ int    law[NODES_PB][8];   // [0..5] words (best-first), [6]=deg
    __shared__ float  lsk[NODES_PB][MAX_DEG];
    __shared__ int    kmx[NODES_PB/2];
    __shared__ float4 lredre[WPB][32], lredim[WPB][32];
    __shared__ float  lsa[WPB], lsa2[WPB];
    __shared__ double dred[256];
    __shared__ float  sreda[256];
    __shared__ double tots[2];

    const int tid = threadIdx.x;
    const int bx  = blockIdx.x;
    const int blk = (bx & (NXCD-1)) * (NBLKF/NXCD) + (bx >> 3);   // XCD-chunked
    const int node0 = blk * NODES_PB;

    // ---- Phase A: T pack + strength for our 128 nodes ----
    {
        const int hw = tid >> 5;                   // 0..7 half-wave
        const int hl = tid & 31;
        #pragma unroll 4
        for (int r = 0; r < NODES_PB/8; ++r) {
            const int node = node0 + r*8 + hw;
            const size_t ro = (size_t)node*HIDDEN + 4*hl;
            const float4 a = *(const float4*)(amp   + ro);
            const float4 p = *(const float4*)(phase + ro);
            const float4 v = *(const float4*)(vel   + ro);
            union { int4 v4; __half2 h[4]; } tt;
            tt.h[0] = __floats2half2_rn(fmaf(0.1f, v.x, p.x), a.x);
            tt.h[1] = __floats2half2_rn(fmaf(0.1f, v.y, p.y), a.y);
            tt.h[2] = __floats2half2_rn(fmaf(0.1f, v.z, p.z), a.z);
            tt.h[3] = __floats2half2_rn(fmaf(0.1f, v.w, p.w), a.w);
            T[(size_t)node*32 + hl] = tt.v4;
            float st = a.x + a.y + a.z + a.w;
            #pragma unroll
            for (int off = 16; off > 0; off >>= 1) st += __shfl_xor(st, off);
            if (hl == 0) strength[node] = st;
        }
    }
    // block 0: prep (pp + mask-layout flag) using LDS scratch
    if (bx == 0) {
        if (tid < HIDDEN) {
            float acc = b_in[tid];
            #pragma unroll 8
            for (int d = 0; d < IN_DIM; ++d) acc = fmaf(W_in[tid*IN_DIM + d], x[d], acc);
            sreda[tid] = fabsf(acc);
            ((float*)law)[tid] = acc;              // sig scratch
        }
        int v = 0;
        #pragma unroll
        for (int r = 0; r < 4; ++r) v |= (int)maskb[(tid + 256*r)*4 + 1];
        ((int*)lredre)[tid] = v;
        __syncthreads();
        for (int s = 64; s > 0; s >>= 1) {
            if (tid < s) sreda[tid] = fmaxf(sreda[tid], sreda[tid + s]);
            __syncthreads();
        }
        for (int s = 128; s > 0; s >>= 1) {
            if (tid < s) ((int*)lredre)[tid] |= ((int*)lredre)[tid + s];
            __syncthreads();
        }
        if (tid < HIDDEN)
            pp[tid] = ((float*)law)[tid] / (sreda[0] + 1e-8f) * 0.314159265358979f;
        if (tid == 0) *flag = (((int*)lredre)[0] != 0) ? 1 : 0;
        __syncthreads();
    }

    grid.sync();   // T, strength, pp, flag ready

    // ---- Phase B: adjacency -> LDS ----
    {
        const int flagv = *flag;
        const int* mi = (const int*)maskb;
        for (int e0 = tid; e0 < NODES_PB*MAX_DEG; e0 += 256) {
            const int n = e0 / MAX_DEG, k = e0 - n*MAX_DEG;
            const int e = (node0 + n)*MAX_DEG + k;
            const int m = flagv ? (maskb[e] != 0) : (mi[e] != 0);
            const int j = nbr_idx[e];
            const float sg = nbr_sign[e];
            law[n][k] = m ? (j | ((sg < 0.0f) ? (1<<24) : 0) | (1<<25)) : 0;
            lsk[n][k] = m ? strength[j] : -3.0e38f;
        }
        __syncthreads();
        if (tid < NODES_PB) {
            int w[MAX_DEG]; float s[MAX_DEG];
            #pragma unroll
            for (int k = 0; k < MAX_DEG; ++k) { w[k] = law[tid][k]; s[k] = lsk[tid][k]; }
            int cw[MAX_DEG]; float cs[MAX_DEG]; int cnt = 0;
            #pragma unroll
            for (int k = 0; k < MAX_DEG; ++k)
                if (w[k] >> 25) { cw[cnt] = w[k]; cs[cnt] = s[k]; ++cnt; }
            int cb = 0; float bv = cs[0];          // deg >= 1 always (ring fix)
            #pragma unroll
            for (int k = 1; k < MAX_DEG; ++k)
                if (k < cnt && cs[k] > bv) { bv = cs[k]; cb = k; }   // first max
            const int tmp = cw[0]; cw[0] = cw[cb]; cw[cb] = tmp;     // best -> slot 0
            #pragma unroll
            for (int k = 0; k < MAX_DEG; ++k)
                if (k >= cnt) cw[k] = node0 + tid;                   // self pad, wt 0
            #pragma unroll
            for (int k = 0; k < MAX_DEG; ++k) law[tid][k] = cw[k];
            law[tid][6] = cnt;
        }
        __syncthreads();
        if (tid < NODES_PB/2) kmx[tid] = max(law[2*tid][6], law[2*tid+1][6]);
        __syncthreads();
    }

    // ---- Phase C: main compute ----
    const int wv   = tid >> 6;
    const int lane = tid & 63;
    const int half = lane >> 5;
    const int lh   = lane & 31;
    const float trev = 0.1f * (float)step[0] * INV2PI;
    const float4 ppv = ((const float4*)pp)[lh];

    float accre[4] = {0,0,0,0}, accim[4] = {0,0,0,0};
    float accsa = 0.f, accsa2 = 0.f;

    #pragma unroll 1
    for (int c = 0; c < CITER; ++c) {
        const int nl = wv*(2*CITER) + 2*c + half;
        const int i  = node0 + nl;
        const int deg  = law[nl][6];
        const int kmax = __builtin_amdgcn_readfirstlane(kmx[wv*CITER + c]);
        const int slots[MAX_DEG] = {law[nl][0], law[nl][1], law[nl][2],
                                    law[nl][3], law[nl][4], law[nl][5]};

        union HT { int4 v4; __half2 h[4]; };
        HT st, nt[MAX_DEG];
        st.v4 = T[(size_t)(unsigned)i*32 + lh];
        #pragma unroll
        for (int k = 0; k < MAX_DEG; ++k)
            if (k < kmax) nt[k].v4 = T[(size_t)(unsigned)(slots[k] & 0xFFFF)*32 + lh];

        float ci[4], si[4], ai[4];
        #pragma unroll
        for (int q = 0; q < 4; ++q) {
            const float2 tq = __half22float2(st.h[q]);
            fsincos(tq.x, si[q], ci[q]);
            ai[q] = tq.y;
        }

        float ir[4] = {0,0,0,0}, ii[4] = {0,0,0,0};
        float cb[4], sb[4], ab[4];
        #pragma unroll
        for (int k = 0; k < MAX_DEG; ++k) {
            if (k < kmax) {
                const int w = slots[k];
                const float vf = (float)((w >> 25) & 1);
                const float sgnm = (w & (1<<24)) ? -vf : vf;
                #pragma unroll
                for (int q = 0; q < 4; ++q) {
                    const float2 tq = __half22float2(nt[k].h[q]);
                    float cj, sj;
                    fsincos(tq.x, sj, cj);
                    const float cosD = ci[q]*cj + si[q]*sj;
                    const float m = cosD * sgnm * tq.y;
                    ir[q] = fmaf(m, cj, ir[q]);
                    ii[q] = fmaf(m, sj, ii[q]);
                    if (k == 0) { cb[q] = cj; sb[q] = sj; ab[q] = tq.y; }
                }
            }
        }

        const float f = 0.03f * __builtin_amdgcn_rcpf((float)deg);
        float nr[4], ni[4];
        #pragma unroll
        for (int q = 0; q < 4; ++q) {
            const float w7 = 0.7f * ai[q];
            nr[q] = fmaf(w7, ci[q], f*ir[q]);
            ni[q] = fmaf(w7, si[q], f*ii[q]);
        }

        const float g2 = (deg >= 2) ? 0.02f : 0.0f;
        #pragma unroll
        for (int q = 0; q < 4; ++q) {
            const float ex = ab[q]*cb[q], ey = ab[q]*sb[q];
            const float im = g2 * __builtin_amdgcn_rsqf(
                fmaxf(nr[q]*nr[q] + ni[q]*ni[q], 1e-30f));
            const float mr = im*(nr[q]*ex + ni[q]*ey);
            const float mi = im*(ni[q]*ex - nr[q]*ey);
            nr[q] += mr; ni[q] += mi;
        }

        const float wr = fmaf((float)i, 1.52587890625e-5f, trev);
        const float wf = 1.0f + 0.02f * __builtin_amdgcn_sinf(wr);
        #pragma unroll
        for (int q = 0; q < 4; ++q) { nr[q] *= wf; ni[q] *= wf; }

        if (i < 32) {
            const float fac = 0.1f / fmaf(0.1f, (float)i, 1.0f);
            const float pv[4] = {ppv.x, ppv.y, ppv.z, ppv.w};
            #pragma unroll
            for (int q = 0; q < 4; ++q) {
                float sp, cp;
                fsincos(pv[q]*fac, sp, cp);
                const float tr = nr[q]*cp - ni[q]*sp;
                ni[q] = ni[q]*cp + nr[q]*sp;
                nr[q] = tr;
            }
        }

        float m[4];
        #pragma unroll
        for (int q = 0; q < 4; ++q) m[q] = sqrtf(nr[q]*nr[q] + ni[q]*ni[q]);
        float lm = fmaxf(fmaxf(m[0], m[1]), fmaxf(m[2], m[3]));
        #pragma unroll
        for (int off = 16; off > 0; off >>= 1) lm = fmaxf(lm, __shfl_xor(lm, off));
        const float sc = 1.0f / (lm + 1e-8f);
        #pragma unroll
        for (int q = 0; q < 4; ++q) {
            accre[q] += nr[q]*sc;
            accim[q] += ni[q]*sc;
            const float Av = m[q]*sc;
            accsa  += Av;
            accsa2 += Av*Av;
        }
    }

    // ---- Phase D: block partials ----
    #pragma unroll
    for (int q = 0; q < 4; ++q) {
        accre[q] += __shfl_xor(accre[q], 32);
        accim[q] += __shfl_xor(accim[q], 32);
    }
    #pragma unroll
    for (int off = 32; off > 0; off >>= 1) {
        accsa  += __shfl_xor(accsa,  off);
        accsa2 += __shfl_xor(accsa2, off);
    }
    __syncthreads();
    if (half == 0) {
        lredre[wv][lh] = make_float4(accre[0], accre[1], accre[2], accre[3]);
        lredim[wv][lh] = make_float4(accim[0], accim[1], accim[2], accim[3]);
    }
    if (lane == 0) { lsa[wv] = accsa; lsa2[wv] = accsa2; }
    __syncthreads();
    if (tid < 32) {
        float4 r = lredre[0][tid], im = lredim[0][tid];
        #pragma unroll
        for (int w = 1; w < WPB; ++w) {
            const float4 a = lredre[w][tid], b = lredim[w][tid];
            r.x += a.x; r.y += a.y; r.z += a.z; r.w += a.w;
            im.x += b.x; im.y += b.y; im.z += b.z; im.w += b.w;
        }
        P[(4*tid  )*NBLKF + blk]       = r.x;
        P[(4*tid+1)*NBLKF + blk]       = r.y;
        P[(4*tid+2)*NBLKF + blk]       = r.z;
        P[(4*tid+3)*NBLKF + blk]       = r.w;
        P[(128+4*tid  )*NBLKF + blk]   = im.x;
        P[(128+4*tid+1)*NBLKF + blk]   = im.y;
        P[(128+4*tid+2)*NBLKF + blk]   = im.z;
        P[(128+4*tid+3)*NBLKF + blk]   = im.w;
    }
    if (tid == 0) {
        p_sa [blk] = lsa[0]  + lsa[1]  + lsa[2]  + lsa[3];
        p_sa2[blk] = lsa2[0] + lsa2[1] + lsa2[2] + lsa2[3];
    }

    grid.sync();

    // ---- Phase E: row reduce (blocks 0..255) ----
    if (bx < 256) {
        double s = 0.0;
        #pragma unroll
        for (int k = 0; k < NBLKF/256; ++k)
            s += (double)P[(size_t)bx*NBLKF + tid + 256*k];
        dred[tid] = s;
        __syncthreads();
        for (int st = 128; st > 0; st >>= 1) {
            if (tid < st) dred[tid] += dred[tid + st];
            __syncthreads();
        }
        if (tid == 0) meanb[bx] = (float)(dred[0] / (double)N_CELLS);
    }

    grid.sync();

    // ---- Phase F: readout (block 0) ----
    if (bx == 0) {
        sreda[tid] = meanb[tid];
        double sa = 0.0, sa2 = 0.0;
        #pragma unroll
        for (int k = 0; k < NBLKF/256; ++k) {
            sa  += (double)p_sa [tid + 256*k];
            sa2 += (double)p_sa2[tid + 256*k];
        }
        dred[tid] = sa;
        __syncthreads();
        for (int s = 128; s > 0; s >>= 1) {
            if (tid < s) dred[tid] += dred[tid + s];
            __syncthreads();
        }
        if (tid == 0) tots[0] = dred[0];
        __syncthreads();
        dred[tid] = sa2;
        __syncthreads();
        for (int s = 128; s > 0; s >>= 1) {
            if (tid < s) dred[tid] += dred[tid + s];
            __syncthreads();
        }
        if (tid == 0) tots[1] = dred[0];
        __syncthreads();

        if (tid < IN_DIM) {
            float acc = b_dec[tid];
            #pragma unroll 8
            for (int c = 0; c < 2*HIDDEN; ++c)
                acc = fmaf(sreda[c], W_dec[tid*2*HIDDEN + c], acc);
            out[tid] = acc;
        }
        if (tid == 0) {
            const double M = (double)N_CELLS * (double)HIDDEN;
            const double var = (tots[1] - tots[0]*tots[0]/M) / (M - 1.0);
            out[IN_DIM] = (float)var;
        }
    }
}

// ========================== FALLBACK (R16, verified) =========================
__global__ __launch_bounds__(256) void k_pre(
    const float* __restrict__ amp, const float* __restrict__ phase,
    const float* __restrict__ vel,
    const float* __restrict__ x, const float* __restrict__ W_in,
    const float* __restrict__ b_in, const unsigned char* __restrict__ maskb,
    int4* __restrict__ T, float* __restrict__ strength,
    float* __restrict__ pp, int* __restrict__ flag)
{
    const int tid = threadIdx.x;
    const int bx  = blockIdx.x;
    if (bx < N_CELLS/8) {
        const int blkp = (bx & (NXCD-1)) * (N_CELLS/8/NXCD) + (bx >> 3);
        const int node = blkp*8 + (tid >> 5);
        const int hl   = tid & 31;
        const size_t ro = (size_t)node*HIDDEN + 4*hl;
        const float4 a = *(const float4*)(amp   + ro);
        const float4 p = *(const float4*)(phase + ro);
        const float4 v = *(const float4*)(vel   + ro);
        union { int4 v4; __half2 h[4]; } tt;
        tt.h[0] = __floats2half2_rn(fmaf(0.1f, v.x, p.x), a.x);
        tt.h[1] = __floats2half2_rn(fmaf(0.1f, v.y, p.y), a.y);
        tt.h[2] = __floats2half2_rn(fmaf(0.1f, v.z, p.z), a.z);
        tt.h[3] = __floats2half2_rn(fmaf(0.1f, v.w, p.w), a.w);
        T[(size_t)node*32 + hl] = tt.v4;
        float st = a.x + a.y + a.z + a.w;
        #pragma unroll
        for (int off = 16; off > 0; off >>= 1) st += __shfl_xor(st, off);
        if (hl == 0) strength[node] = st;
        return;
    }
    __shared__ float sig[HIDDEN];
    __shared__ float red[HIDDEN];
    __shared__ int fl[256];
    if (tid < HIDDEN) {
        float acc = b_in[tid];
        #pragma unroll 8
        for (int d = 0; d < IN_DIM; ++d) acc = fmaf(W_in[tid*IN_DIM + d], x[d], acc);
        sig[tid] = acc;
        red[tid] = fabsf(acc);
    }
    int v = 0;
    #pragma unroll
    for (int r = 0; r < 4; ++r) v |= (int)maskb[(tid + 256*r)*4 + 1];
    fl[tid] = v;
    __syncthreads();
    for (int s = 64; s > 0; s >>= 1) {
        if (tid < s) red[tid] = fmaxf(red[tid], red[tid + s]);
        __syncthreads();
    }
    for (int s = 128; s > 0; s >>= 1) {
        if (tid < s) fl[tid] |= fl[tid + s];
        __syncthreads();
    }
    if (tid < HIDDEN) pp[tid] = sig[tid] / (red[0] + 1e-8f) * 0.314159265358979f;
    if (tid == 0) *flag = (fl[0] != 0) ? 1 : 0;
}

__global__ __launch_bounds__(256) void k_adj(
    const int* __restrict__ nbr_idx, const float* __restrict__ nbr_sign,
    const void* __restrict__ nbr_mask, const int* __restrict__ flagp,
    const float* __restrict__ strength, int4* __restrict__ adj)
{
    __shared__ int   lw[256][MAX_DEG];
    __shared__ float ls[256][MAX_DEG];
    __shared__ int   ldeg[256];
    const int t = threadIdx.x;
    const int bx = blockIdx.x;
    const int blkp = (bx & (NXCD-1)) * (N_CELLS/256/NXCD) + (bx >> 3);
    const int i = blkp*256 + t;
    const int flagv = *flagp;
    const unsigned char* mb = (const unsigned char*)nbr_mask;
    const int*           mi = (const int*)nbr_mask;
    int cnt = 0;
    #pragma unroll
    for (int k = 0; k < MAX_DEG; ++k) {
        const int e = i*MAX_DEG + k;
        const int m = flagv ? (mb[e] != 0) : (mi[e] != 0);
        const int j = nbr_idx[e];
        const float sg = nbr_sign[e];
        if (m) {
            lw[t][cnt] = j | ((sg < 0.0f) ? (1<<24) : 0) | (1<<25);
            ls[t][cnt] = strength[j];
            ++cnt;
        }
    }
    int cb = 0; float bv = ls[t][0];
    #pragma unroll
    for (int k = 1; k < MAX_DEG; ++k)
        if (k < cnt && ls[t][k] > bv) { bv = ls[t][k]; cb = k; }
    if (cb != 0) {
        const int tmp = lw[t][0];
        lw[t][0] = lw[t][cb];
        lw[t][cb] = tmp;
    }
    #pragma unroll
    for (int k = 0; k < MAX_DEG; ++k) if (k >= cnt) lw[t][k] = i;
    ldeg[t] = cnt;
    __syncthreads();
    const int kmax = max(cnt, ldeg[t ^ 1]);
    adj[2*(size_t)i    ] = make_int4(lw[t][0], lw[t][1], lw[t][2], lw[t][3]);
    adj[2*(size_t)i + 1] = make_int4(lw[t][4], lw[t][5], cnt, kmax);
}

__global__ __launch_bounds__(256) void k_mainc(
    const int4* __restrict__ T, const int4* __restrict__ adj,
    const int* __restrict__ step, const float* __restrict__ pp,
    float* __restrict__ P, float* __restrict__ p_sa, float* __restrict__ p_sa2)
{
    __shared__ float4 lredre[WPB][32], lredim[WPB][32];
    __shared__ float  lsa[WPB], lsa2[WPB];

    const int tid   = threadIdx.x;
    const int bx    = blockIdx.x;
    const int blk   = (bx & (NXCD-1)) * (NBLK_B/NXCD) + (bx >> 3);
    const int node0 = blk * NPB_B;

    const int wv   = tid >> 6;
    const int lane = tid & 63;
    const int half = lane >> 5;
    const int lh   = lane & 31;
    const float trev = 0.1f * (float)step[0] * INV2PI;
    const float4 ppv = ((const float4*)pp)[lh];

    float accre[4] = {0,0,0,0}, accim[4] = {0,0,0,0};
    float accsa = 0.f, accsa2 = 0.f;

    const int nlbase = wv*(2*CHUNK_B) + half;
    int4 A0n = adj[2*(size_t)(node0 + nlbase)    ];
    int4 A1n = adj[2*(size_t)(node0 + nlbase) + 1];

    #pragma unroll 1
    for (int c = 0; c < CHUNK_B; ++c) {
        const int nl = nlbase + 2*c;
        const int i  = node0 + nl;
        const int4 A0 = A0n, A1 = A1n;
        if (c + 1 < CHUNK_B) {
            A0n = adj[2*(size_t)(i + 2)    ];
            A1n = adj[2*(size_t)(i + 2) + 1];
        }
        const int deg  = A1.z;
        const int kmax = __builtin_amdgcn_readfirstlane(A1.w);
        const int slots[MAX_DEG] = {A0.x, A0.y, A0.z, A0.w, A1.x, A1.y};

        union HT { int4 v4; __half2 h[4]; };
        HT st, nt[MAX_DEG];
        st.v4 = T[(size_t)(unsigned)i*32 + lh];
        #pragma unroll
        for (int k = 0; k < MAX_DEG; ++k)
            if (k < kmax) nt[k].v4 = T[(size_t)(unsigned)(slots[k] & 0xFFFF)*32 + lh];

        float ci[4], si[4], ai[4];
        #pragma unroll
        for (int q = 0; q < 4; ++q) {
            const float2 tq = __half22float2(st.h[q]);
            fsincos(tq.x, si[q], ci[q]);
            ai[q] = tq.y;
        }

        float ir[4] = {0,0,0,0}, ii[4] = {0,0,0,0};
        float cb[4], sb[4], ab[4];
        #pragma unroll
        for (int k = 0; k < MAX_DEG; ++k) {
            if (k < kmax) {
                const int w = slots[k];
                const float vf = (float)((w >> 25) & 1);
                const float sgnm = (w & (1<<24)) ? -vf : vf;
                #pragma unroll
                for (int q = 0; q < 4; ++q) {
                    const float2 tq = __half22float2(nt[k].h[q]);
                    float cj, sj;
                    fsincos(tq.x, sj, cj);
                    const float cosD = ci[q]*cj + si[q]*sj;
                    const float m = cosD * sgnm * tq.y;
                    ir[q] = fmaf(m, cj, ir[q]);
                    ii[q] = fmaf(m, sj, ii[q]);
                    if (k == 0) { cb[q] = cj; sb[q] = sj; ab[q] = tq.y; }
                }
            }
        }

        const float f = 0.03f * __builtin_amdgcn_rcpf((float)deg);
        float nr[4], ni[4];
        #pragma unroll
        for (int q = 0; q < 4; ++q) {
            const float w7 = 0.7f * ai[q];
            nr[q] = fmaf(w7, ci[q], f*ir[q]);
            ni[q] = fmaf(w7, si[q], f*ii[q]);
        }

        const float g2 = (deg >= 2) ? 0.02f : 0.0f;
        #pragma unroll
        for (int q = 0; q < 4; ++q) {
            const float ex = ab[q]*cb[q], ey = ab[q]*sb[q];
            const float im = g2 * __builtin_amdgcn_rsqf(
                fmaxf(nr[q]*nr[q] + ni[q]*ni[q], 1e-30f));
            const float mr = im*(nr[q]*ex + ni[q]*ey);
            const float mi = im*(ni[q]*ex - nr[q]*ey);
            nr[q] += mr; ni[q] += mi;
        }

        const float wr = fmaf((float)i, 1.52587890625e-5f, trev);
        const float wf = 1.0f + 0.02f * __builtin_amdgcn_sinf(wr);
        #pragma unroll
        for (int q = 0; q < 4; ++q) { nr[q] *= wf; ni[q] *= wf; }

        if (i < 32) {
            const float fac = 0.1f / fmaf(0.1f, (float)i, 1.0f);
            const float pv[4] = {ppv.x, ppv.y, ppv.z, ppv.w};
            #pragma unroll
            for (int q = 0; q < 4; ++q) {
                float sp, cp;
                fsincos(pv[q]*fac, sp, cp);
                const float tr = nr[q]*cp - ni[q]*sp;
                ni[q] = ni[q]*cp + nr[q]*sp;
                nr[q] = tr;
            }
        }

        float m[4];
        #pragma unroll
        for (int q = 0; q < 4; ++q) m[q] = sqrtf(nr[q]*nr[q] + ni[q]*ni[q]);
        float lm = fmaxf(fmaxf(m[0], m[1]), fmaxf(m[2], m[3]));
        #pragma unroll
        for (int off = 16; off > 0; off >>= 1) lm = fmaxf(lm, __shfl_xor(lm, off));
        const float sc = 1.0f / (lm + 1e-8f);
        #pragma unroll
        for (int q = 0; q < 4; ++q) {
            accre[q] += nr[q]*sc;
            accim[q] += ni[q]*sc;
            const float Av = m[q]*sc;
            accsa  += Av;
            accsa2 += Av*Av;
        }
    }

    #pragma unroll
    for (int q = 0; q < 4; ++q) {
        accre[q] += __shfl_xor(accre[q], 32);
        accim[q] += __shfl_xor(accim[q], 32);
    }
    #pragma unroll
    for (int off = 32; off > 0; off >>= 1) {
        accsa  += __shfl_xor(accsa,  off);
        accsa2 += __shfl_xor(accsa2, off);
    }
    if (half == 0) {
        lredre[wv][lh] = make_float4(accre[0], accre[1], accre[2], accre[3]);
        lredim[wv][lh] = make_float4(accim[0], accim[1], accim[2], accim[3]);
    }
    if (lane == 0) { lsa[wv] = accsa; lsa2[wv] = accsa2; }
    __syncthreads();
    if (tid < 32) {
        float4 r = lredre[0][tid], im = lredim[0][tid];
        #pragma unroll
        for (int w = 1; w < WPB; ++w) {
            const float4 a = lredre[w][tid], b = lredim[w][tid];
            r.x += a.x; r.y += a.y; r.z += a.z; r.w += a.w;
            im.x += b.x; im.y += b.y; im.z += b.z; im.w += b.w;
        }
        P[(4*tid  )*NBLK_B + blk]       = r.x;
        P[(4*tid+1)*NBLK_B + blk]       = r.y;
        P[(4*tid+2)*NBLK_B + blk]       = r.z;
        P[(4*tid+3)*NBLK_B + blk]       = r.w;
        P[(128+4*tid  )*NBLK_B + blk]   = im.x;
        P[(128+4*tid+1)*NBLK_B + blk]   = im.y;
        P[(128+4*tid+2)*NBLK_B + blk]   = im.z;
        P[(128+4*tid+3)*NBLK_B + blk]   = im.w;
    }
    if (tid == 0) {
        p_sa [blk] = lsa[0]  + lsa[1]  + lsa[2]  + lsa[3];
        p_sa2[blk] = lsa2[0] + lsa2[1] + lsa2[2] + lsa2[3];
    }
}

__global__ void k_red(const float* __restrict__ P, float* __restrict__ mean)
{
    __shared__ double red[256];
    const int r = blockIdx.x, tid = threadIdx.x;
    double s = 0.0;
    #pragma unroll
    for (int k = 0; k < NBLK_B/256; ++k) s += (double)P[(size_t)r*NBLK_B + tid + 256*k];
    red[tid] = s;
    __syncthreads();
    for (int st = 128; st > 0; st >>= 1) { if (tid < st) red[tid] += red[tid + st]; __syncthreads(); }
    if (tid == 0) mean[r] = (float)(red[0] / (double)N_CELLS);
}

__global__ void k_final(const float* __restrict__ mean_in,
                        const float* __restrict__ p_sa, const float* __restrict__ p_sa2,
                        const float* __restrict__ W_dec, const float* __restrict__ b_dec,
                        float* __restrict__ out)
{
    __shared__ float  mean[2*HIDDEN];
    __shared__ double dred[256];
    __shared__ double tots[2];
    const int tid = threadIdx.x;
    mean[tid] = mean_in[tid];
    double sa = 0.0, sa2 = 0.0;
    #pragma unroll
    for (int k = 0; k < NBLK_B/256; ++k) {
        sa  += (double)p_sa [tid + 256*k];
        sa2 += (double)p_sa2[tid + 256*k];
    }
    dred[tid] = sa;
    __syncthreads();
    for (int s = 128; s > 0; s >>= 1) { if (tid < s) dred[tid] += dred[tid + s]; __syncthreads(); }
    if (tid == 0) tots[0] = dred[0];
    __syncthreads();
    dred[tid] = sa2;
    __syncthreads();
    for (int s = 128; s > 0; s >>= 1) { if (tid < s) dred[tid] += dred[tid + s]; __syncthreads(); }
    if (tid == 0) tots[1] = dred[0];
    __syncthreads();

    if (tid < IN_DIM) {
        float acc = b_dec[tid];
        #pragma unroll 8
        for (int c = 0; c < 2*HIDDEN; ++c) acc = fmaf(mean[c], W_dec[tid*2*HIDDEN + c], acc);
        out[tid] = acc;
    }
    if (tid == 0) {
        const double M = (double)N_CELLS * (double)HIDDEN;
        const double var = (tots[1] - tots[0]*tots[0]/M) / (M - 1.0);
        out[IN_DIM] = (float)var;
    }
}

extern "C" void kernel_launch(void* const* d_in, const int* in_sizes, int n_in,
                              void* d_out, int out_size, void* d_ws, size_t ws_size,
                              hipStream_t stream)
{
    const float* x       = (const float*)d_in[0];
    const float* amp     = (const float*)d_in[1];
    const float* phs     = (const float*)d_in[2];
    const float* vel     = (const float*)d_in[3];
    const int*   nbr_idx = (const int*)d_in[4];
    const float* nbr_sgn = (const float*)d_in[5];
    const void*  nbr_msk = d_in[6];
    const float* W_in    = (const float*)d_in[7];
    const float* b_in    = (const float*)d_in[8];
    const float* W_dec   = (const float*)d_in[9];
    const float* b_dec   = (const float*)d_in[10];
    const int*   step    = (const int*)d_in[11];

    char* wsb = (char*)d_ws;
    float* pp    = (float*)(wsb + WS_PP);
    int*   flag  = (int*)  (wsb + WS_FLAG);
    float* strg  = (float*)(wsb + WS_STR);
    int4*  T     = (int4*) (wsb + WS_T);
    int4*  adjv  = (int4*) (wsb + WS_ADJ);
    float* P     = (float*)(wsb + WS_P);
    float* p_sa  = (float*)(wsb + WS_SA);
    float* p_sa2 = (float*)(wsb + WS_SA2);
    float* meanb = (float*)(wsb + WS_MEAN);
    float* out   = (float*)d_out;

    const unsigned char* maskb = (const unsigned char*)nbr_msk;

    void* args[] = {
        (void*)&amp, (void*)&phs, (void*)&vel,
        (void*)&x, (void*)&W_in, (void*)&b_in, (void*)&maskb,
        (void*)&nbr_idx, (void*)&nbr_sgn, (void*)&step,
        (void*)&T, (void*)&strg, (void*)&pp, (void*)&flag,
        (void*)&P, (void*)&p_sa, (void*)&p_sa2, (void*)&meanb,
        (void*)&W_dec, (void*)&b_dec, (void*)&out
    };
    hipError_t err = hipLaunchCooperativeKernel((void*)k_fused, dim3(NBLKF),
                                                dim3(256), args, 0, stream);
    if (err != hipSuccess) {
        // deterministic fallback: verified R16 5-kernel pipeline
        k_pre<<<N_CELLS/8 + 1, 256, 0, stream>>>(amp, phs, vel, x, W_in, b_in,
                                                 maskb, T, strg, pp, flag);
        k_adj<<<N_CELLS/256, 256, 0, stream>>>(nbr_idx, nbr_sgn, nbr_msk, flag,
                                               strg, adjv);
        k_mainc<<<NBLK_B, 256, 0, stream>>>(T, adjv, step, pp, P, p_sa, p_sa2);
        k_red<<<256, 256, 0, stream>>>(P, meanb);
        k_final<<<1, 256, 0, stream>>>(meanb, p_sa, p_sa2, W_dec, b_dec, out);
    }
}